// Round 9
// baseline (200.731 us; speedup 1.0000x reference)
//
#include <hip/hip_runtime.h>

// Problem constants (match reference file)
constexpr int B = 32768;
constexpr int D = 1024;
constexpr int S = 64;
constexpr int O = 4;

// ---------------------------------------------------------------------------
// R9 = R8 (190.2us: W^T in LDS, ballot-compaction, nt x-loads, 12-shuffle
// reduce) with the x stream moved to a DMA ring: per-wave 2-slot LDS ring
// filled by __builtin_amdgcn_global_load_lds (1 row = 4 x 1KB instructions,
// linear LDS dest = wave-uniform base + lane*16 -- exactly our mapping),
// drained with COUNTED vmcnt (steady vmcnt(5): row k+1's 4 loads + the out
// store stay in flight; never vmcnt(0) in the loop).
//
// Why: R8 confirmed the x path is read-concurrency-limited (nt = -10us).
// The single-xb register pipeline caps depth at 1 row/wave (64-VGPR budget:
// R4 spilled at 2 buffers; R6's forced 128-reg lost occupancy).  The DMA
// ring gives 2 rows (8KB) per wave continuously in flight with ZERO VGPR
// cost.  12 waves/CU x ~8KB ~= 96KB/CU outstanding vs ~9KB needed for
// 6 TB/s.  Compute path identical to R8 except xv comes from a conflict-free
// lane*16 ds_read_b128.
//
// Sync discipline (rule 18 / T3-T4): every inline-asm s_waitcnt is followed
// by sched_barrier(0).  Slot reuse is WAR-safe: ds_read results are drained
// to VGPRs (compiler lgkmcnt before FMA use) before the overwriting DMA
// issues.  vmcnt FIFO audit:
//   prologue: issue row0(4), row1(4)                 -> outstanding 8
//   iter k=0:        wait vmcnt(4) (cnt>1) / vmcnt(0)(cnt==1)
//   iter 0<k<cnt-1:  outstanding = loads(k)4 + store(k-1)1 + loads(k+1)4 = 9
//                    wait vmcnt(5) drains exactly loads(k) (oldest)
//   iter k=cnt-1:    outstanding = loads(k)4 + store(k-1)1 -> wait vmcnt(1)
// ---------------------------------------------------------------------------

constexpr int CHUNKS      = 32;             // chunks per subject
constexpr int CHUNK       = B / CHUNKS;     // 1024 rows per block
constexpr int SEG         = CHUNK / 4;      // 256 rows per wave
constexpr int MAIN_BLOCKS = S * CHUNKS;     // 2048 blocks

typedef float f4 __attribute__((ext_vector_type(4)));

__global__ __launch_bounds__(256) void main_kernel(
    const float* __restrict__ x,      // [B, D]
    const int*   __restrict__ sid,    // [B]
    const float* __restrict__ W,      // [S, D, O]
    const float* __restrict__ bias,   // [S, O]
    float*       __restrict__ out)    // [B, O]
{
    __shared__ float          Wt[O * D];        // 16 KB: plane o at Wt[o*1024+d]
    __shared__ unsigned short list[4][SEG];     //  2 KB: per-wave match lists
    __shared__ float          xring[4][2][D];   // 32 KB: [wave][slot][float]

    const int t    = threadIdx.x;
    const int lane = t & 63;
    const int wave = t >> 6;
    const int s    = blockIdx.x >> 5;         // 32 consecutive blocks share s
    const int c    = blockIdx.x & 31;
    const int q    = lane >> 4;               // output index this lane stores

    // ---- 1. Stage W[s]^T into LDS (coalesced float4 reads; scalar writes
    //         bank = d%32 = t%32, 2 lanes/bank = free). ----
    {
        const f4* Wp = (const f4*)(W + (size_t)s * (D * O));
        #pragma unroll
        for (int r = 0; r < 4; ++r) {
            const int d = r * 256 + t;
            const f4 w4 = Wp[d];              // W[s][d][0..3]
            Wt[0 * D + d] = w4.x;
            Wt[1 * D + d] = w4.y;
            Wt[2 * D + d] = w4.z;
            Wt[3 * D + d] = w4.w;
        }
    }

    // ---- 2. Scan my 256-row sid segment, ballot-compact matches into the
    //         wave-private list. ----
    const int seg = c * CHUNK + wave * SEG;
    int cnt = 0;
    #pragma unroll
    for (int r = 0; r < 4; ++r) {
        const int i = seg + r * 64 + lane;                 // coalesced 256B
        const bool m = (sid[i] == s);
        const unsigned long long mask = __ballot(m);
        const int rank = __popcll(mask & ((1ull << lane) - 1ull));
        if (m) list[wave][cnt + rank] = (unsigned short)i;
        cnt += __popcll(mask);                             // lane-uniform
    }

    const float bb = bias[(s << 2) + q];

    __syncthreads();                          // Wt visible to all waves
    if (cnt == 0) return;                     // wave-uniform exit

    const f4* Wt4 = (const f4*)Wt;            // plane o at f4 index o*256

    // DMA one 4KB row into ring slot: 4 instructions of 64 lanes x 16B.
    // Global addr is per-lane (base + j*256 + 4*lane floats); LDS dest is
    // wave-uniform (slot base + j*1024 bytes); HW places lane l at +16*l,
    // reproducing the row linearly.  aux=2 = NT (R8-proven streaming hint).
#define ISSUE_ROW(ROW, SLOT) do {                                              \
        const float* _g = x + ((size_t)(ROW) << 10) + 4 * lane;                \
        _Pragma("unroll")                                                      \
        for (int _j = 0; _j < 4; ++_j)                                         \
            __builtin_amdgcn_global_load_lds(                                  \
                (const __attribute__((address_space(1))) unsigned int*)        \
                    (_g + _j * 256),                                           \
                (__attribute__((address_space(3))) unsigned int*)              \
                    (&xring[wave][(SLOT)][_j * 256]),                          \
                16, 0, 2);                                                     \
    } while (0)

#define VMWAIT(N) do {                                                         \
        asm volatile("s_waitcnt vmcnt(" #N ")" ::: "memory");                  \
        __builtin_amdgcn_sched_barrier(0);                                     \
    } while (0)

    // ---- 3. Prologue: fill both ring slots. ----
    int rowCur = __builtin_amdgcn_readfirstlane((int)list[wave][0]);
    ISSUE_ROW(rowCur, 0);
    int rowNext = rowCur;
    if (cnt > 1) {
        rowNext = __builtin_amdgcn_readfirstlane((int)list[wave][1]);
        ISSUE_ROW(rowNext, 1);
    }

    // ---- 4. Steady loop: wait(counted) -> ds_read+FMA -> reduce -> store
    //         -> refill just-consumed slot with row k+2. ----
    #pragma unroll 1
    for (int k = 0; k < cnt; ++k) {
        if (k == 0) {
            if (cnt > 1) VMWAIT(4);
            else         VMWAIT(0);
        } else if (k < cnt - 1) {
            VMWAIT(5);
        } else {
            VMWAIT(1);
        }

        const f4* xs = (const f4*)&xring[wave][k & 1][0];

        float a0 = 0.f, a1 = 0.f, a2 = 0.f, a3 = 0.f;
        #pragma unroll
        for (int j = 0; j < 4; ++j) {
            const f4 xv = xs[64 * j + lane];             // ds_read_b128,
            const f4 w0 = Wt4[0 * 256 + 64 * j + lane];  // all lane*16 stride
            const f4 w1 = Wt4[1 * 256 + 64 * j + lane];  // = conflict-free
            const f4 w2 = Wt4[2 * 256 + 64 * j + lane];
            const f4 w3 = Wt4[3 * 256 + 64 * j + lane];
            a0 += xv.x * w0.x; a1 += xv.x * w1.x;
            a2 += xv.x * w2.x; a3 += xv.x * w3.x;
            a0 += xv.y * w0.y; a1 += xv.y * w1.y;
            a2 += xv.y * w2.y; a3 += xv.y * w3.y;
            a0 += xv.z * w0.z; a1 += xv.z * w1.z;
            a2 += xv.z * w2.z; a3 += xv.z * w3.z;
            a0 += xv.w * w0.w; a1 += xv.w * w1.w;
            a2 += xv.w * w2.w; a3 += xv.w * w3.w;
        }

        // 12-op reduce: xor{16,32} on 4 accs -> per-(lane%16) partials;
        // lane picks q = lane>>4; xor{1,2,4,8} sums the 16 residues.
        #pragma unroll
        for (int m = 16; m <= 32; m <<= 1) {
            a0 += __shfl_xor(a0, m, 64);
            a1 += __shfl_xor(a1, m, 64);
            a2 += __shfl_xor(a2, m, 64);
            a3 += __shfl_xor(a3, m, 64);
        }
        float v = (q == 0) ? a0 : (q == 1) ? a1 : (q == 2) ? a2 : a3;
        #pragma unroll
        for (int m = 1; m <= 8; m <<= 1)
            v += __shfl_xor(v, m, 64);

        if ((lane & 15) == 0)                 // lanes 0,16,32,48 -> o = 0..3
            __builtin_nontemporal_store(v + bb,
                                        &out[((size_t)rowCur << 2) + q]);

        if (k + 2 < cnt) {
            const int rowP =
                __builtin_amdgcn_readfirstlane((int)list[wave][k + 2]);
            ISSUE_ROW(rowP, k & 1);           // reuse just-consumed slot
            rowCur = rowNext;
            rowNext = rowP;
        } else {
            rowCur = rowNext;
        }
    }

#undef ISSUE_ROW
#undef VMWAIT
}

extern "C" void kernel_launch(void* const* d_in, const int* in_sizes, int n_in,
                              void* d_out, int out_size, void* d_ws, size_t ws_size,
                              hipStream_t stream) {
    const float* x    = (const float*)d_in[0];   // [B, D]
    const int*   sid  = (const int*)d_in[1];     // [B]
    const float* W    = (const float*)d_in[2];   // [S, D, O]
    const float* bias = (const float*)d_in[3];   // [S, O]
    float* out = (float*)d_out;                  // [B, O]

    main_kernel<<<MAIN_BLOCKS, 256, 0, stream>>>(x, sid, W, bias, out);
}

// Round 10
// 187.080 us; speedup vs baseline: 1.0730x; 1.0730x over previous
//
#include <hip/hip_runtime.h>

// Problem constants (match reference file)
constexpr int B = 32768;
constexpr int D = 1024;
constexpr int S = 64;
constexpr int O = 4;

// ---------------------------------------------------------------------------
// R10 = R8's exact steady body (best, 190.2us: W^T in LDS, ballot compaction,
// NON-TEMPORAL x register loads, 12-shuffle reduce, 64-VGPR/32-waves-per-CU)
// plus two LOAD-BALANCE changes motivated by the R8 residual (~35us custom vs
// ~22us ideal; in-flight bytes were ample so MLP was not the gap):
//
//  1. CHUNKS 32 -> 64: 4096 blocks (2x oversubscribed).  R8's 2048 blocks
//     were exactly co-resident -> zero backfill -> slowest CU (+3sigma of
//     Binomial row counts ~ +27%) set the kernel time.  With 2 rounds of
//     blocks the HW scheduler backfills early CUs; imbalance shrinks to a
//     one-block tail.  Extra W-stage traffic (32->64MB) is L2-resident and
//     R7 proved prologue traffic is not the limiter.
//  2. Block-shared virtual list: the 4 waves' matches concatenate; wave w
//     processes entries w, w+4, w+8...  Intra-block wave imbalance
//     (sigma=2 rows) drops to +-1 row.
//
// R9 lesson folded in: do NOT grow LDS (50KB ring halved occupancy, -10us).
// LDS here = 16KB Wt + 1KB list + 16B counts = 17.3KB -> still 8 blocks/CU.
// ---------------------------------------------------------------------------

constexpr int CHUNKS      = 64;             // chunks per subject
constexpr int CHUNK       = B / CHUNKS;     // 512 rows per block
constexpr int WSEG        = CHUNK / 4;      // 128 rows scanned per wave
constexpr int MAIN_BLOCKS = S * CHUNKS;     // 4096 blocks

typedef float f4 __attribute__((ext_vector_type(4)));

__global__ __launch_bounds__(256) void main_kernel(
    const float* __restrict__ x,      // [B, D]
    const int*   __restrict__ sid,    // [B]
    const float* __restrict__ W,      // [S, D, O]
    const float* __restrict__ bias,   // [S, O]
    float*       __restrict__ out)    // [B, O]
{
    __shared__ float          Wt[O * D];        // 16 KB: plane o at Wt[o*1024+d]
    __shared__ unsigned short wlist[4][WSEG];   //  1 KB: per-wave match lists
    __shared__ int            wcnt[4];

    const int t    = threadIdx.x;
    const int lane = t & 63;
    const int wave = t >> 6;
    const int s    = blockIdx.x >> 6;         // 64 consecutive blocks share s
    const int c    = blockIdx.x & 63;
    const int q    = lane >> 4;               // output index this lane stores

    // ---- 1. Stage W[s]^T into LDS (coalesced float4 reads; scalar writes
    //         bank = d%32 = t%32, 2 lanes/bank = free). ----
    {
        const f4* Wp = (const f4*)(W + (size_t)s * (D * O));
        #pragma unroll
        for (int r = 0; r < 4; ++r) {
            const int d = r * 256 + t;
            const f4 w4 = Wp[d];              // W[s][d][0..3]
            Wt[0 * D + d] = w4.x;
            Wt[1 * D + d] = w4.y;
            Wt[2 * D + d] = w4.z;
            Wt[3 * D + d] = w4.w;
        }
    }

    // ---- 2. Scan my 128-row sid segment, ballot-compact into my list. ----
    const int seg = c * CHUNK + wave * WSEG;
    int cnt = 0;
    #pragma unroll
    for (int r = 0; r < 2; ++r) {
        const int i = seg + r * 64 + lane;                 // coalesced 256B
        const bool m = (sid[i] == s);
        const unsigned long long mask = __ballot(m);
        const int rank = __popcll(mask & ((1ull << lane) - 1ull));
        if (m) wlist[wave][cnt + rank] = (unsigned short)i;
        cnt += __popcll(mask);                             // lane-uniform
    }
    if (lane == 0) wcnt[wave] = cnt;

    const float bb = bias[(s << 2) + q];

    __syncthreads();                          // Wt + wlist + wcnt visible

    // ---- 3. Virtual concatenated list; wave w takes entries w, w+4, ... ----
    const int c0 = wcnt[0], c1 = wcnt[1], c2 = wcnt[2], c3 = wcnt[3];
    const int p1 = c0, p2 = c0 + c1, p3 = c0 + c1 + c2;
    const int total = p3 + c3;

#define ROW_OF(G, DST) do {                                                    \
        int _g = (G), _r;                                                      \
        if      (_g < p1) _r = wlist[0][_g];                                   \
        else if (_g < p2) _r = wlist[1][_g - p1];                              \
        else if (_g < p3) _r = wlist[2][_g - p2];                              \
        else              _r = wlist[3][_g - p3];                              \
        (DST) = __builtin_amdgcn_readfirstlane(_r);                            \
    } while (0)

    int g = wave;
    if (g >= total) return;                   // wave-uniform exit

    // ---- 4. R8's proven steady loop: nt register loads, FMA from LDS-W,
    //         12-shuffle reduce, prefetch-next into the single xb. ----
    int rowC;
    ROW_OF(g, rowC);
    f4 xb[4];
    {
        const f4* xr = (const f4*)(x + ((size_t)rowC << 10));
        #pragma unroll
        for (int j = 0; j < 4; ++j)
            xb[j] = __builtin_nontemporal_load(xr + 64 * j + lane);
    }

    const f4* Wt4 = (const f4*)Wt;            // plane o at f4 index o*256

    #pragma unroll 1
    for (; g < total; g += 4) {
        const bool more = (g + 4 < total);
        int rowN = rowC;
        if (more) ROW_OF(g + 4, rowN);

        float a0 = 0.f, a1 = 0.f, a2 = 0.f, a3 = 0.f;
        #pragma unroll
        for (int j = 0; j < 4; ++j) {
            const f4 xv = xb[j];
            const f4 w0 = Wt4[0 * 256 + 64 * j + lane];  // 16B lane stride,
            const f4 w1 = Wt4[1 * 256 + 64 * j + lane];  // conflict-free
            const f4 w2 = Wt4[2 * 256 + 64 * j + lane];
            const f4 w3 = Wt4[3 * 256 + 64 * j + lane];
            a0 += xv.x * w0.x; a1 += xv.x * w1.x;
            a2 += xv.x * w2.x; a3 += xv.x * w3.x;
            a0 += xv.y * w0.y; a1 += xv.y * w1.y;
            a2 += xv.y * w2.y; a3 += xv.y * w3.y;
            a0 += xv.z * w0.z; a1 += xv.z * w1.z;
            a2 += xv.z * w2.z; a3 += xv.z * w3.z;
            a0 += xv.w * w0.w; a1 += xv.w * w1.w;
            a2 += xv.w * w2.w; a3 += xv.w * w3.w;
        }

        if (more) {                            // prefetch next row's x (nt)
            const f4* xr = (const f4*)(x + ((size_t)rowN << 10));
            #pragma unroll
            for (int j = 0; j < 4; ++j)
                xb[j] = __builtin_nontemporal_load(xr + 64 * j + lane);
        }

        // 12-op reduce: xor{16,32} on 4 accs -> per-(lane%16) partials;
        // lane picks q = lane>>4; xor{1,2,4,8} sums the 16 residues.
        #pragma unroll
        for (int m = 16; m <= 32; m <<= 1) {
            a0 += __shfl_xor(a0, m, 64);
            a1 += __shfl_xor(a1, m, 64);
            a2 += __shfl_xor(a2, m, 64);
            a3 += __shfl_xor(a3, m, 64);
        }
        float v = (q == 0) ? a0 : (q == 1) ? a1 : (q == 2) ? a2 : a3;
        #pragma unroll
        for (int m = 1; m <= 8; m <<= 1)
            v += __shfl_xor(v, m, 64);

        if ((lane & 15) == 0)                 // lanes 0,16,32,48 -> o = 0..3
            out[((size_t)rowC << 2) + q] = v + bb;

        rowC = rowN;
    }

#undef ROW_OF
}

extern "C" void kernel_launch(void* const* d_in, const int* in_sizes, int n_in,
                              void* d_out, int out_size, void* d_ws, size_t ws_size,
                              hipStream_t stream) {
    const float* x    = (const float*)d_in[0];   // [B, D]
    const int*   sid  = (const int*)d_in[1];     // [B]
    const float* W    = (const float*)d_in[2];   // [S, D, O]
    const float* bias = (const float*)d_in[3];   // [S, O]
    float* out = (float*)d_out;                  // [B, O]

    main_kernel<<<MAIN_BLOCKS, 256, 0, stream>>>(x, sid, W, bias, out);
}